// Round 8
// baseline (2321.651 us; speedup 1.0000x reference)
//
#include <hip/hip_runtime.h>
#include <math.h>

// ---------------- problem constants ----------------
#define FC     65            // freq bins in H
#define NB     97            // output samples per frame (lossy irfft n)
#define KB     49            // bins actually used = NB//2+1
#define FRAME  64
#define B_     32
#define F_     4000
#define OUT_LEN ((F_ - 1) * FRAME + NB)   // 256033
#define CHUNK  63                          // OUTPUT frames per block (lane0 redundant)
#define NCHUNK 64
#define KP     100                         // padded row stride
#define SB     69                          // bufA row stride (odd-ish: 2-way banks, free)

// ws layout (floats), rows stacked contiguously (226 rows x 100):
//   D: rows 0..63, W: rows 64..128, E: rows 129..225 (pads 98/99 = 0)
#define D_OFF  0
#define W_OFF  (64 * KP)
#define E_OFF  (129 * KP)

#define N_D    (64 * KB)
#define N_E    (97 * KB)
#define N_W    (65 * KB)
#define N_ALL  (N_D + N_E + N_W)
#define N_PADZ (226 * 2)
#define N_INIT (N_ALL + N_PADZ)

// ---------- init kernel; W via fp64 recurrences (no libm in loop) ----------
__global__ void fn_init(float* __restrict__ ws) {
    int tid = blockIdx.x * blockDim.x + threadIdx.x;
    if (tid < N_D) {
        int j = tid / KB, k = tid % KB;
        double x = -(double)(k * j) / 96.0;
        ws[D_OFF + j * KP + 2 * k]     = (float)cospi(x);
        ws[D_OFF + j * KP + 2 * k + 1] = (float)sinpi(x);
    } else if (tid < N_D + N_E) {
        int t2 = tid - N_D;
        int t = t2 / KB, k = t2 % KB;
        double g = 0.01 / 97.0;
        double x = 2.0 * (double)(k * t) / 97.0;
        ws[E_OFF + t * KP + 2 * k]     = (float)(g * (k == 0 ? 1.0 : 2.0) * cospi(x));
        ws[E_OFF + t * KP + 2 * k + 1] = (float)(k == 0 ? 0.0 : -2.0 * g * sinpi(x));
    } else if (tid < N_ALL) {
        int t2 = tid - (N_D + N_E);
        int kap = t2 / KB, k = t2 % KB;
        double sr_ = cospi(-(double)k / 96.0), si_ = sinpi(-(double)k / 96.0);
        double er = 1.0, ei = 0.0;
        double C2 = 2.0 * cospi(2.0 * (double)kap / 129.0);
        double c_prev = cospi(-130.0 * (double)kap / 129.0);
        double c_cur  = cospi(-128.0 * (double)kap / 129.0);
        double U2 = 2.0 * cospi(2.0 / 129.0);
        double u_prev = cospi(2.0 / 129.0);
        double u_cur  = 1.0;
        double accr = 0.0, acci = 0.0;
        for (int m = 0; m < 129; m++) {
            double win = 0.5 * (1.0 - u_cur);
            double a = win * (1.0 / 129.0);
            if (kap) a *= 2.0 * c_cur;
            accr += a * er; acci += a * ei;
            double un = U2 * u_cur - u_prev; u_prev = u_cur; u_cur = un;
            double cn = C2 * c_cur - c_prev; c_prev = c_cur; c_cur = cn;
            double e2r = er * sr_ - ei * si_;
            double e2i = er * si_ + ei * sr_;
            er = e2r; ei = e2i;
        }
        ws[W_OFF + kap * KP + 2 * k]     = (float)accr;
        ws[W_OFF + kap * KP + 2 * k + 1] = (float)acci;
    } else if (tid < N_INIT) {
        int z = tid - N_ALL;
        ws[(z >> 1) * KP + 98 + (z & 1)] = 0.0f;
    }
}

// ---------------- repetition macros (literal indices only) ----------------
#define R64(M) M(0) M(1) M(2) M(3) M(4) M(5) M(6) M(7) M(8) M(9) M(10) M(11) M(12) \
 M(13) M(14) M(15) M(16) M(17) M(18) M(19) M(20) M(21) M(22) M(23) M(24) M(25) M(26) \
 M(27) M(28) M(29) M(30) M(31) M(32) M(33) M(34) M(35) M(36) M(37) M(38) M(39) M(40) \
 M(41) M(42) M(43) M(44) M(45) M(46) M(47) M(48) M(49) M(50) M(51) M(52) M(53) M(54) \
 M(55) M(56) M(57) M(58) M(59) M(60) M(61) M(62) M(63)
#define R65(M) R64(M) M(64)
#define R49(M) M(0) M(1) M(2) M(3) M(4) M(5) M(6) M(7) M(8) M(9) M(10) M(11) M(12) \
 M(13) M(14) M(15) M(16) M(17) M(18) M(19) M(20) M(21) M(22) M(23) M(24) M(25) M(26) \
 M(27) M(28) M(29) M(30) M(31) M(32) M(33) M(34) M(35) M(36) M(37) M(38) M(39) M(40) \
 M(41) M(42) M(43) M(44) M(45) M(46) M(47) M(48)
#define R49E(M) M(0) M(2) M(4) M(6) M(8) M(10) M(12) M(14) M(16) M(18) M(20) M(22) \
 M(24) M(26) M(28) M(30) M(32) M(34) M(36) M(38) M(40) M(42) M(44) M(46) M(48)
#define R49O(M) M(1) M(3) M(5) M(7) M(9) M(11) M(13) M(15) M(17) M(19) M(21) M(23) \
 M(25) M(27) M(29) M(31) M(33) M(35) M(37) M(39) M(41) M(43) M(45) M(47)
#define Q1(M) M(0) M(1) M(2) M(3) M(4) M(5) M(6) M(7) M(8) M(9) M(10) M(11) M(12)
#define Q2(M) M(13) M(14) M(15) M(16) M(17) M(18) M(19) M(20) M(21) M(22) M(23) M(24)
#define Q3(M) M(25) M(26) M(27) M(28) M(29) M(30) M(31) M(32) M(33) M(34) M(35) M(36)
#define Q4(M) M(37) M(38) M(39) M(40) M(41) M(42) M(43) M(44) M(45) M(46) M(47) M(48)
#define GA(M)  M(0) M(1) M(2) M(3) M(4) M(5) M(6) M(7) M(8) M(9) M(10) M(11) M(12) \
 M(13) M(14) M(15) M(16) M(17) M(18) M(19) M(20) M(21) M(22) M(23) M(24) M(25) M(26) \
 M(27) M(28) M(29) M(30) M(31) M(32)
#define GB(M)  M(33) M(34) M(35) M(36) M(37) M(38) M(39) M(40) M(41) M(42) M(43) \
 M(44) M(45) M(46) M(47) M(48) M(49) M(50) M(51) M(52) M(53) M(54) M(55) M(56) M(57) \
 M(58) M(59) M(60) M(61) M(62) M(63) M(64) M(65)
#define GBW(M) M(33) M(34) M(35) M(36) M(37) M(38) M(39) M(40) M(41) M(42) M(43) \
 M(44) M(45) M(46) M(47) M(48) M(49) M(50) M(51) M(52) M(53) M(54) M(55) M(56) M(57) \
 M(58) M(59) M(60) M(61) M(62) M(63)
#define GC(M)  M(66) M(67) M(68) M(69) M(70) M(71) M(72) M(73) M(74) M(75) M(76) \
 M(77) M(78) M(79) M(80) M(81) M(82) M(83) M(84) M(85) M(86) M(87) M(88) M(89) M(90) \
 M(91) M(92) M(93) M(94) M(95) M(96)

// ---------- main: 1 wave/block; inputs in registers, matrices via s_load ----------
__launch_bounds__(64, 2)
__global__ void fn_main_kernel(const float* __restrict__ H,
                               const float* __restrict__ noise,
                               const float* __restrict__ ws,
                               float* __restrict__ out) {
    __shared__ float bufA[64 * SB];       // 17.7 KB: noise -> H -> obuf (stride 69)

    int bid = blockIdx.x;
    int b = bid >> 6;
    int c = bid & 63;
    int f0 = c * CHUNK;
    int nf = min(CHUNK, F_ - f0);
    int L = threadIdx.x;                  // lane computes frame f0-1+L
    int fMine = f0 - 1 + L;
    const float* wsD = ws + D_OFF;        // wave-uniform bases -> s_load w/ imm
    const float* wsW = ws + W_OFF;
    const float* wsE = ws + E_OFF;
    const long lastTail = (long)b * OUT_LEN + (long)(F_ - 1) * FRAME;

    // ---- phase 0: stage noise frames f0-1 .. f0+62 (row i, stride 69) ----
    long nbase = ((long)b * F_ + (f0 - 1)) * FRAME;
    const long nmax = (long)B_ * F_ * FRAME - 1;
#pragma unroll 1
    for (int i = 0; i < 64; i++) {
        long g = nbase + (long)i * 64 + L;
        g = g < 0 ? 0 : (g > nmax ? nmax : g);
        float v = 2.0f * noise[g] - 1.0f;
        if (c == 0 && i == 0) v = 0.0f;   // frame -1: N=0 -> X=0
        bufA[i * SB + L] = v;
    }
    __syncthreads();

    // ---- preload my frame's noise into 64 named registers ----
#define DECLN(j) const float n##j = bufA[L * SB + (j)];
    R64(DECLN)
#undef DECLN
    __syncthreads();

    // ---- X state: 98 named scalars ----
#define DECLX(k) float Nr##k = 0.0f, Ni##k = 0.0f;
    R49(DECLX)
#undef DECLX

    // ---- phase 1: straight-line DFT, matrices via uniform s_load ----
#define F1(k) Nr##k = fmaf(nj_, d_[2*(k)], Nr##k); Ni##k = fmaf(nj_, d_[2*(k)+1], Ni##k);
#define T1(j) { const float nj_ = n##j; const float* d_ = wsD + (j)*KP; R49(F1) }
    R64(T1)
#undef T1
#undef F1

    // ---- phase 2: stage H (coalesced linear load, scatter to stride-69 rows) ----
    long hbase = ((long)b * F_ + (f0 - 1)) * FC;
    const long hmax = (long)B_ * F_ * FC - 1;
#pragma unroll 1
    for (int i = 0; i < 65; i++) {
        int e = i * 64 + L;               // 0..4159
        long g = hbase + e;
        g = g < 0 ? 0 : (g > hmax ? hmax : g);
        int f = e / 65;                   // magic-mul
        int k2 = e - f * 65;
        bufA[f * SB + k2] = H[g];
    }
    __syncthreads();

    // ---- preload my frame's H into 65 named registers ----
#define DECLH(k) const float h##k = bufA[L * SB + (k)];
    R65(DECLH)
#undef DECLH
    __syncthreads();

    // ---- phase 3+4: R = W.h in 4 bin-quarters (caps live regs), X = N*R ----
#define DECLR(k) float Rr##k = 0.0f, Ri##k = 0.0f;
#define F3(k) Rr##k = fmaf(hk_, w_[2*(k)], Rr##k); Ri##k = fmaf(hk_, w_[2*(k)+1], Ri##k);
#define P4(k) { float xr_ = Nr##k * Rr##k - Ni##k * Ri##k; \
                Ni##k = Nr##k * Ri##k + Ni##k * Rr##k; Nr##k = xr_; }
#define T3(kap) { const float hk_ = h##kap; const float* w_ = wsW + (kap)*KP; Q1(F3) }
    { Q1(DECLR) R65(T3) Q1(P4) }
#undef T3
#define T3(kap) { const float hk_ = h##kap; const float* w_ = wsW + (kap)*KP; Q2(F3) }
    { Q2(DECLR) R65(T3) Q2(P4) }
#undef T3
#define T3(kap) { const float hk_ = h##kap; const float* w_ = wsW + (kap)*KP; Q3(F3) }
    { Q3(DECLR) R65(T3) Q3(P4) }
#undef T3
#define T3(kap) { const float hk_ = h##kap; const float* w_ = wsW + (kap)*KP; Q4(F3) }
    { Q4(DECLR) R65(T3) Q4(P4) }
#undef T3
#undef DECLR
#undef F3
#undef P4
    __syncthreads();                      // bufA becomes obuf (rows stride 69)

    // ---- phase 5: y[t] = E[t].X in 3 t-groups of 33, y in named registers ----
#define F5E(k) ar0 = fmaf(Nr##k, e_[2*(k)], ar0); ai0 = fmaf(Ni##k, e_[2*(k)+1], ai0);
#define F5O(k) ar1 = fmaf(Nr##k, e_[2*(k)], ar1); ai1 = fmaf(Ni##k, e_[2*(k)+1], ai1);
#define T5(t) { const float* e_ = wsE + (t)*KP; \
                float ar0 = 0.f, ai0 = 0.f, ar1 = 0.f, ai1 = 0.f; \
                R49E(F5E) R49O(F5O) \
                y##t = (ar0 + ar1) + (ai0 + ai1); }
#define DECLY(t) float y##t;
#define WHEAD(t) if (L) bufA[(L - 1) * SB + (t)] = y##t;
#define WTAIL(t) { float p_ = __shfl_up(y##t, 1); \
                   if (L) bufA[(L - 1) * SB + ((t) - 64)] += p_; \
                   if (fMine == F_ - 1) out[lastTail + (t)] = y##t; }
    { GA(DECLY) GA(T5) GA(WHEAD) }
    { GB(DECLY) GB(T5) GBW(WHEAD) WTAIL(64) WTAIL(65) }
    { GC(DECLY) GC(T5) GC(WTAIL) }
#undef T5
#undef DECLY
#undef WHEAD
#undef WTAIL
#undef F5E
#undef F5O
    __syncthreads();

    // ---- phase 6: coalesced 256B wave stores ----
    long obase2 = (long)b * OUT_LEN + (long)f0 * FRAME;
#pragma unroll 1
    for (int i = 0; i < nf; i++) {
        out[obase2 + (long)i * 64 + L] = bufA[i * SB + L];
    }
}

extern "C" void kernel_launch(void* const* d_in, const int* in_sizes, int n_in,
                              void* d_out, int out_size, void* d_ws, size_t ws_size,
                              hipStream_t stream) {
    const float* H     = (const float*)d_in[0];   // (32, 4000, 65) fp32
    const float* noise = (const float*)d_in[1];   // (32, 4000, 64) fp32
    float* out = (float*)d_out;                   // (32, 256033) fp32
    float* ws  = (float*)d_ws;                    // matrices, 226*100 floats

    fn_init<<<(N_INIT + 255) / 256, 256, 0, stream>>>(ws);
    fn_main_kernel<<<B_ * NCHUNK, 64, 0, stream>>>(H, noise, ws, out);
}